// Round 3
// baseline (417.309 us; speedup 1.0000x reference)
//
#include <hip/hip_runtime.h>
#include <hip/hip_bf16.h>
#include <math.h>

#define NN 8192
#define EE 32768
#define WN 2560

typedef unsigned short u16;
typedef unsigned int u32;

__device__ __forceinline__ float bfu(u16 u) { return __uint_as_float(((u32)u) << 16); }

// Runtime-dtype load helpers. F32=true -> input arrays are fp32; false -> bf16.
template<bool F32> __device__ __forceinline__ float ld(const void* p, int i) {
    if (F32) return ((const float*)p)[i];
    return bfu(((const u16*)p)[i]);
}
// two consecutive elements i, i+1 (i must be even for the bf16 path)
template<bool F32> __device__ __forceinline__ float2 ld2(const void* p, int i) {
    if (F32) {
        const float* f = (const float*)p + i;
        float2 r; r.x = f[0]; r.y = f[1]; return r;
    }
    u32 pr = *(const u32*)((const u16*)p + i);
    float2 r; r.x = __uint_as_float(pr << 16); r.y = __uint_as_float(pr & 0xffff0000u);
    return r;
}
// dtype probe: means = linspace(e^-5, 1, 16). fp32 read at float-index 7 ->
// 0.470 if fp32 array; ~1.0019 if packed bf16. uniform branch.
__device__ __forceinline__ bool probe_f32(const void* means) {
    float m = ((const float*)means)[7];
    return (m < 0.7f);
}

// ---------------------------------------------------------------------------
// Edge kernel body: 1024 WGs x 256 threads, 32 edges per WG.
// Phase A: geometry, rbf, hid (silu MLP layer 1), epilogue coefficients -> LDS
// Phase B: 10 chunks of 256 columns: ew chunk = hid @ W2[:,chunk] + b2 -> LDS,
//          then region-specific contraction into per-thread message registers.
// Final: atomicAdd messages into agg[N][80], counts into cnt[N].
// ---------------------------------------------------------------------------
template<bool F32>
__device__ __forceinline__ void edge_body(
    const void* __restrict__ h, const void* __restrict__ pos, const int* __restrict__ ei,
    const void* __restrict__ means, const void* __restrict__ betas,
    const void* __restrict__ W1, const void* __restrict__ b1,
    const void* __restrict__ W2, const void* __restrict__ b2,
    float* __restrict__ agg, float* __restrict__ cnt)
{
    __shared__ float sh_hid[64][32];   // [h][edge] transposed for broadcast float4 reads
    __shared__ float sh_s[32][32];     // s_src
    __shared__ float sh_dot[32][16];   // (v . y1)/sqrt(3)
    __shared__ float sh_v[32][48];     // v_src  (u*3+d)
    __shared__ float sh_cross[32][48]; // cross(v,y1)/sqrt(2)
    __shared__ float sh_y1[32][3];
    __shared__ float sh_geo[32][2];    // expd, cut
    __shared__ float sh_q2[32][16];    // sum_u s[u]*w_sv[u][w]
    __shared__ int   sh_src[32];
    __shared__ int   sh_dst[32];
    __shared__ float sh_ew[32][256];   // ew column chunk

    const int t = threadIdx.x;

    // ---- A1: per-edge geometry (threads 0..31) ----
    if (t < 32) {
        const int eg = (blockIdx.x << 5) + t;
        const int si = ei[eg];
        const int di = ei[EE + eg];
        float ax = ld<F32>(pos, si*3+0), ay = ld<F32>(pos, si*3+1), az = ld<F32>(pos, si*3+2);
        float bx = ld<F32>(pos, di*3+0), by = ld<F32>(pos, di*3+1), bz = ld<F32>(pos, di*3+2);
        float vx = bx-ax, vy = by-ay, vz = bz-az;
        float d = sqrtf(vx*vx + vy*vy + vz*vz + 1e-12f);
        float invd = 1.7320508075688772f / d;      // sqrt(3)/d
        sh_y1[t][0] = vx*invd; sh_y1[t][1] = vy*invd; sh_y1[t][2] = vz*invd;
        sh_geo[t][0] = expf(-d);                   // ALPHA = 1
        sh_geo[t][1] = (d < 5.0f) ? 0.5f*(cosf(d*0.6283185307179586f) + 1.0f) : 0.0f;
        sh_src[t] = si; sh_dst[t] = di;
    }
    __syncthreads();

    // ---- A2: rbf + hid + coefficients (8 threads per edge) ----
    {
        const int e = t >> 3, r = t & 7;
        const float expd = sh_geo[e][0], cut = sh_geo[e][1];
        float rbf[16];
        #pragma unroll
        for (int k = 0; k < 16; ++k) {
            float mm = ld<F32>(means, k), bb = ld<F32>(betas, k);
            float td = expd - mm;
            rbf[k] = expf(-bb*td*td) * cut;
        }
        #pragma unroll
        for (int jj = 0; jj < 8; ++jj) {
            int j = (r << 3) + jj;
            float a = ld<F32>(b1, j);
            #pragma unroll
            for (int k = 0; k < 16; ++k) a += rbf[k] * ld<F32>(W1, (k<<6) + j);
            sh_hid[j][e] = a / (1.0f + expf(-a));   // silu
        }
        const int srcn = sh_src[e];
        const int hrow = srcn*80;
        const float y1x = sh_y1[e][0], y1y = sh_y1[e][1], y1z = sh_y1[e][2];
        #pragma unroll
        for (int i = 0; i < 4; ++i) { int u = (r<<2)+i; sh_s[e][u] = ld<F32>(h, hrow+u); }
        #pragma unroll
        for (int i = 0; i < 2; ++i) {
            int u = (r<<1)+i;
            float v0 = ld<F32>(h, hrow+32+u*3+0);
            float v1 = ld<F32>(h, hrow+32+u*3+1);
            float v2 = ld<F32>(h, hrow+32+u*3+2);
            sh_v[e][u*3+0] = v0; sh_v[e][u*3+1] = v1; sh_v[e][u*3+2] = v2;
            sh_dot[e][u] = (v0*y1x + v1*y1y + v2*y1z) * 0.5773502691896258f; // /sqrt(3)
            sh_cross[e][u*3+0] = (v1*y1z - v2*y1y) * 0.7071067811865476f;    // /sqrt(2)
            sh_cross[e][u*3+1] = (v2*y1x - v0*y1z) * 0.7071067811865476f;
            sh_cross[e][u*3+2] = (v0*y1y - v1*y1x) * 0.7071067811865476f;
        }
    }

    // ---- Phase B: column chunks ----
    float outs[4] = {0.f,0.f,0.f,0.f};
    float q2r[2]  = {0.f,0.f};
    float outv[6] = {0.f,0.f,0.f,0.f,0.f,0.f};
    const int g = t >> 7;     // edge group: 0 -> edges 0..15, 1 -> edges 16..31
    const int l = t & 127;    // columns 2l, 2l+1 within chunk

    for (int ci = 0; ci < 10; ++ci) {
        __syncthreads();      // sh_ew reuse barrier (also publishes phase A at ci=0)
        const int c0 = ci << 8;
        const int cA = c0 + (l << 1);
        float acc0[16], acc1[16];
        {
            float2 bp = ld2<F32>(b2, cA);
            #pragma unroll
            for (int e2 = 0; e2 < 16; ++e2) { acc0[e2] = bp.x; acc1[e2] = bp.y; }
        }
        #pragma unroll 2
        for (int hh = 0; hh < 64; ++hh) {
            float2 wv = ld2<F32>(W2, hh*WN + cA);
            float wa = wv.x, wb = wv.y;
            const float4* hp = (const float4*)&sh_hid[hh][g << 4];
            #pragma unroll
            for (int q4 = 0; q4 < 4; ++q4) {
                float4 hv4 = hp[q4];
                acc0[q4*4+0] += hv4.x*wa; acc1[q4*4+0] += hv4.x*wb;
                acc0[q4*4+1] += hv4.y*wa; acc1[q4*4+1] += hv4.y*wb;
                acc0[q4*4+2] += hv4.z*wa; acc1[q4*4+2] += hv4.z*wb;
                acc0[q4*4+3] += hv4.w*wa; acc1[q4*4+3] += hv4.w*wb;
            }
        }
        #pragma unroll
        for (int e2 = 0; e2 < 16; ++e2) {
            float2 st; st.x = acc0[e2]; st.y = acc1[e2];
            *(float2*)&sh_ew[(g<<4)+e2][l<<1] = st;
        }
        __syncthreads();

        // ---- chunk epilogue (region-uniform per chunk) ----
        if (ci < 4) {                       // w_ss: u = ci*8 + j (of 32), w in 0..32
            const int ub = ci << 3;
            #pragma unroll
            for (int k = 0; k < 4; ++k) {
                int p = t + (k<<8); int e = p >> 5; int w = p & 31;
                float s = 0.f;
                #pragma unroll
                for (int j = 0; j < 8; ++j) s += sh_s[e][ub+j] * sh_ew[e][(j<<5)+w];
                outs[k] += 0.125f * s;      // 1/(sqrt(32)*sqrt(2))
            }
        } else if (ci < 6) {                // w_sv: u = (ci-4)*16 + j (of 32), w in 0..16
            const int ub = (ci-4) << 4;
            #pragma unroll
            for (int k = 0; k < 2; ++k) {
                int q = t + (k<<8); int e = q >> 4; int w = q & 15;
                float s = 0.f;
                #pragma unroll
                for (int j = 0; j < 16; ++j) s += sh_s[e][ub+j] * sh_ew[e][(j<<4)+w];
                q2r[k] += s;
            }
            if (ci == 5) {
                #pragma unroll
                for (int k = 0; k < 2; ++k) { int q = t + (k<<8); sh_q2[q>>4][q&15] = q2r[k]; }
            }
        } else if (ci == 6) {               // w_vs: u in 0..16, w in 0..16
            #pragma unroll
            for (int k = 0; k < 6; ++k) {
                int p = t + (k<<8); int e = p/48; int m = p - e*48; int w = m/3; int d = m - w*3;
                float s = 0.f;
                #pragma unroll
                for (int u = 0; u < 16; ++u) s += sh_v[e][u*3+d] * sh_ew[e][(u<<4)+w];
                outv[k] += 0.14433756729740643f * s;   // 1/(sqrt(16)*sqrt(3))
            }
        } else if (ci < 9) {                // w_vv0: u = (ci-7)*8 + j (of 16), w in 0..32
            const int ub = (ci-7) << 3;
            #pragma unroll
            for (int k = 0; k < 4; ++k) {
                int p = t + (k<<8); int e = p >> 5; int w = p & 31;
                float s = 0.f;
                #pragma unroll
                for (int j = 0; j < 8; ++j) s += sh_dot[e][ub+j] * sh_ew[e][(j<<5)+w];
                outs[k] += 0.17677669529663687f * s;   // 1/(sqrt(16)*sqrt(2))
            }
        } else {                            // w_vv1: u in 0..16, w in 0..16 (cross)
            #pragma unroll
            for (int k = 0; k < 6; ++k) {
                int p = t + (k<<8); int e = p/48; int m = p - e*48; int w = m/3; int d = m - w*3;
                float s = 0.f;
                #pragma unroll
                for (int u = 0; u < 16; ++u) s += sh_cross[e][u*3+d] * sh_ew[e][(u<<4)+w];
                outv[k] += 0.14433756729740643f * s;
            }
        }
    }

    // ---- final: scatter messages ----
    #pragma unroll
    for (int k = 0; k < 4; ++k) {
        int p = t + (k<<8); int e = p >> 5; int w = p & 31;
        atomicAdd(&agg[sh_dst[e]*80 + w], outs[k]);
    }
    #pragma unroll
    for (int k = 0; k < 6; ++k) {
        int p = t + (k<<8); int e = p/48; int m = p - e*48; int w = m/3; int d = m - w*3;
        float val = outv[k] + sh_q2[e][w]*sh_y1[e][d]*0.10206207261596574f; // 1/sqrt(96)
        atomicAdd(&agg[sh_dst[e]*80 + 32 + m], val);
    }
    if (t < 32) atomicAdd(&cnt[sh_dst[t]], 1.0f);
}

__global__ __launch_bounds__(256, 2) void edge_kernel(
    const void* __restrict__ h, const void* __restrict__ pos, const int* __restrict__ ei,
    const void* __restrict__ means, const void* __restrict__ betas,
    const void* __restrict__ W1, const void* __restrict__ b1,
    const void* __restrict__ W2, const void* __restrict__ b2,
    float* __restrict__ agg, float* __restrict__ cnt)
{
    if (probe_f32(means)) edge_body<true >(h, pos, ei, means, betas, W1, b1, W2, b2, agg, cnt);
    else                  edge_body<false>(h, pos, ei, means, betas, W1, b1, W2, b2, agg, cnt);
}

// ---------------------------------------------------------------------------
// Node kernel: out = agg/max(cnt,1) + self_interaction + h  (fp32 out)
// ---------------------------------------------------------------------------
template<bool F32>
__device__ __forceinline__ void node_body(
    const void* __restrict__ h, const void* __restrict__ Wss, const void* __restrict__ Wvv,
    const float* __restrict__ agg, const float* __restrict__ cnt,
    float* __restrict__ out)
{
    const int idx = blockIdx.x*256 + threadIdx.x;
    const int n = idx / 80;
    const int j = idx - n*80;
    float a = agg[idx] / fmaxf(cnt[n], 1.0f);
    const int hrow = n*80;
    float si = 0.f;
    if (j < 32) {
        #pragma unroll
        for (int u = 0; u < 32; ++u) si += ld<F32>(h, hrow+u) * ld<F32>(Wss, (u<<5)+j);
        si *= 0.17677669529663687f;   // 1/sqrt(32)
    } else {
        int m = j - 32; int w = m/3; int d = m - w*3;
        #pragma unroll
        for (int u = 0; u < 16; ++u) si += ld<F32>(h, hrow+32+u*3+d) * ld<F32>(Wvv, (u<<4)+w);
        si *= 0.25f;                  // 1/sqrt(16)
    }
    out[idx] = a + si + ld<F32>(h, hrow+j);
}

__global__ __launch_bounds__(256, 4) void node_kernel(
    const void* __restrict__ h, const void* __restrict__ Wss, const void* __restrict__ Wvv,
    const void* __restrict__ means,
    const float* __restrict__ agg, const float* __restrict__ cnt,
    float* __restrict__ out)
{
    if (probe_f32(means)) node_body<true >(h, Wss, Wvv, agg, cnt, out);
    else                  node_body<false>(h, Wss, Wvv, agg, cnt, out);
}

extern "C" void kernel_launch(void* const* d_in, const int* in_sizes, int n_in,
                              void* d_out, int out_size, void* d_ws, size_t ws_size,
                              hipStream_t stream) {
    const void* h     = d_in[0];
    const void* pos   = d_in[1];
    const int*  ei    = (const int*)d_in[2];
    const void* means = d_in[3];
    const void* betas = d_in[4];
    const void* W1    = d_in[5];
    const void* b1    = d_in[6];
    const void* W2    = d_in[7];
    const void* b2    = d_in[8];
    const void* Wss   = d_in[9];
    const void* Wvv   = d_in[10];

    float* agg = (float*)d_ws;
    float* cnt = agg + (size_t)NN*80;

    hipMemsetAsync(d_ws, 0, (size_t)(NN*80 + NN)*sizeof(float), stream);
    hipLaunchKernelGGL(edge_kernel, dim3(EE/32), dim3(256), 0, stream,
                       h, pos, ei, means, betas, W1, b1, W2, b2, agg, cnt);
    hipLaunchKernelGGL(node_kernel, dim3((NN*80)/256), dim3(256), 0, stream,
                       h, Wss, Wvv, means, agg, cnt, (float*)d_out);
}

// Round 4
// 155.586 us; speedup vs baseline: 2.6822x; 2.6822x over previous
//
#include <hip/hip_runtime.h>
#include <math.h>

#define NN 8192
#define EE 32768
#define WN 2560
#define EW_STRIDE 260            // sh_ew row stride (floats), padded: bank = (4e+c)%32
#define HID_STRIDE 72            // sh_hidb row stride (bf16), 144 B = 9x16 B, conflict-free frags

typedef unsigned short u16;
typedef unsigned int u32;
typedef short short8 __attribute__((ext_vector_type(8)));   // 8 bf16 = 4 VGPR (MFMA A/B frag)
typedef float f32x4 __attribute__((ext_vector_type(4)));    // MFMA C/D frag

__device__ __forceinline__ u16 f2b(float f) {               // fp32 -> bf16 RNE
    u32 x = __float_as_uint(f);
    return (u16)((x + 0x7fffu + ((x >> 16) & 1u)) >> 16);
}

// ---------------------------------------------------------------------------
// W2 [64][2560] fp32  ->  W2T [2560][64] bf16 (k contiguous per column).
// LDS-tiled transpose: coalesced reads (256B/wave) and writes (128B/wave).
// ---------------------------------------------------------------------------
__global__ __launch_bounds__(256) void w2_transpose(const float* __restrict__ W2,
                                                    u16* __restrict__ W2T) {
    __shared__ float tile[64][65];
    const int c0 = blockIdx.x << 6;
    const int t = threadIdx.x;
    const int tl = t & 63, th = t >> 6;
    #pragma unroll
    for (int r = 0; r < 16; ++r) {
        int k = (r << 2) + th;
        tile[k][tl] = W2[k * WN + c0 + tl];
    }
    __syncthreads();
    #pragma unroll
    for (int r = 0; r < 16; ++r) {
        int c = (r << 2) + th;
        W2T[(size_t)(c0 + c) * 64 + tl] = f2b(tile[tl][c]);
    }
}

// ---------------------------------------------------------------------------
// Edge kernel: 1024 WGs x 256 threads (4 waves), 32 edges per WG.
// Phase A: geometry, rbf, hid (-> bf16 LDS), epilogue coefficients -> LDS.
// Phase B: 10 chunks of 256 cols: ew = hid(32x64) @ W2T via mfma 16x16x32 bf16
//          (A-frags cached in regs; B-frags coalesced dwordx4 from L2-resident
//          W2T; C + b2 -> sh_ew), then region-uniform contraction epilogue.
// Final: atomicAdd messages into agg[N][80], counts into cnt[N].
// ---------------------------------------------------------------------------
__global__ __launch_bounds__(256, 2) void edge_kernel(
    const float* __restrict__ h, const float* __restrict__ pos, const int* __restrict__ ei,
    const float* __restrict__ means, const float* __restrict__ betas,
    const float* __restrict__ W1, const float* __restrict__ b1,
    const u16* __restrict__ W2T, const float* __restrict__ b2,
    float* __restrict__ agg, float* __restrict__ cnt)
{
    __shared__ alignas(16) u16 sh_hidb[32 * HID_STRIDE]; // hid bf16, row stride 72
    __shared__ float sh_s[32][32];     // s_src
    __shared__ float sh_dot[32][16];   // (v . y1)/sqrt(3)
    __shared__ float sh_v[32][48];     // v_src (u*3+d)
    __shared__ float sh_cross[32][48]; // cross(v,y1)/sqrt(2)
    __shared__ float sh_y1[32][3];
    __shared__ float sh_geo[32][2];    // expd, cut
    __shared__ float sh_q2[32][16];    // sum_u s[u]*w_sv[u][w]
    __shared__ int   sh_src[32];
    __shared__ int   sh_dst[32];
    __shared__ float sh_ew[32 * EW_STRIDE];   // ew column chunk

    const int t = threadIdx.x;

    // ---- A1: per-edge geometry (threads 0..31) ----
    if (t < 32) {
        const int eg = (blockIdx.x << 5) + t;
        const int si = ei[eg];
        const int di = ei[EE + eg];
        float ax = pos[si*3+0], ay = pos[si*3+1], az = pos[si*3+2];
        float bx = pos[di*3+0], by = pos[di*3+1], bz = pos[di*3+2];
        float vx = bx-ax, vy = by-ay, vz = bz-az;
        float d = sqrtf(vx*vx + vy*vy + vz*vz + 1e-12f);
        float invd = 1.7320508075688772f / d;      // sqrt(3)/d
        sh_y1[t][0] = vx*invd; sh_y1[t][1] = vy*invd; sh_y1[t][2] = vz*invd;
        sh_geo[t][0] = expf(-d);                   // ALPHA = 1
        sh_geo[t][1] = (d < 5.0f) ? 0.5f*(cosf(d*0.6283185307179586f) + 1.0f) : 0.0f;
        sh_src[t] = si; sh_dst[t] = di;
    }
    __syncthreads();

    // ---- A2: rbf + hid(bf16) + coefficients (8 threads per edge) ----
    {
        const int e = t >> 3, r = t & 7;
        const float expd = sh_geo[e][0], cut = sh_geo[e][1];
        float rbf[16];
        #pragma unroll
        for (int k = 0; k < 16; ++k) {
            float td = expd - means[k];
            rbf[k] = expf(-betas[k]*td*td) * cut;
        }
        short8 pk;
        #pragma unroll
        for (int jj = 0; jj < 8; ++jj) {
            int j = (r << 3) + jj;
            float a = b1[j];
            #pragma unroll
            for (int k = 0; k < 16; ++k) a += rbf[k] * W1[(k<<6) + j];
            float s = a / (1.0f + expf(-a));        // silu
            pk[jj] = (short)f2b(s);
        }
        *(short8*)&sh_hidb[e*HID_STRIDE + (r<<3)] = pk;   // 16B store, 2-way banks

        const int srcn = sh_src[e];
        const float* hrow = h + srcn*80;
        const float y1x = sh_y1[e][0], y1y = sh_y1[e][1], y1z = sh_y1[e][2];
        #pragma unroll
        for (int i = 0; i < 4; ++i) { int u = (r<<2)+i; sh_s[e][u] = hrow[u]; }
        #pragma unroll
        for (int i = 0; i < 2; ++i) {
            int u = (r<<1)+i;
            float v0 = hrow[32+u*3+0];
            float v1 = hrow[32+u*3+1];
            float v2 = hrow[32+u*3+2];
            sh_v[e][u*3+0] = v0; sh_v[e][u*3+1] = v1; sh_v[e][u*3+2] = v2;
            sh_dot[e][u] = (v0*y1x + v1*y1y + v2*y1z) * 0.5773502691896258f; // /sqrt(3)
            sh_cross[e][u*3+0] = (v1*y1z - v2*y1y) * 0.7071067811865476f;    // /sqrt(2)
            sh_cross[e][u*3+1] = (v2*y1x - v0*y1z) * 0.7071067811865476f;
            sh_cross[e][u*3+2] = (v0*y1y - v1*y1x) * 0.7071067811865476f;
        }
    }
    __syncthreads();   // publish phase A (sh_hidb + coefficient arrays)

    // ---- A-fragments: hid rows, cached for all 160 column tiles ----
    const int ln = t & 63, wv = t >> 6;
    const int quad = ln >> 4, lm = ln & 15;
    short8 af[2][2];   // [M-tile][K-step]; A[m=lm][k=ks*32+quad*8+j]
    #pragma unroll
    for (int mt = 0; mt < 2; ++mt)
        #pragma unroll
        for (int ks = 0; ks < 2; ++ks)
            af[mt][ks] = *(const short8*)&sh_hidb[(mt*16+lm)*HID_STRIDE + (ks<<5) + (quad<<3)];

    // ---- Phase B: column chunks ----
    float outs[4] = {0.f,0.f,0.f,0.f};
    float q2r[2]  = {0.f,0.f};
    float outv[6] = {0.f,0.f,0.f,0.f,0.f,0.f};

    for (int ci = 0; ci < 10; ++ci) {
        if (ci) __syncthreads();          // previous epilogue done before rewriting sh_ew

        // B-frags for this wave's 4 column tiles (coalesced 16B/lane from W2T)
        short8 bf[4][2];
        float b2v[4];
        #pragma unroll
        for (int i = 0; i < 4; ++i) {
            const int coll = (((wv<<2)+i)<<4) + lm;        // 0..255 within chunk
            const int col  = (ci<<8) + coll;
            #pragma unroll
            for (int ks = 0; ks < 2; ++ks)
                bf[i][ks] = *(const short8*)(W2T + (size_t)col*64 + (ks<<5) + (quad<<3));
            b2v[i] = b2[col];
        }
        f32x4 d[4][2];
        #pragma unroll
        for (int i = 0; i < 4; ++i) {
            d[i][0] = (f32x4){0.f,0.f,0.f,0.f};
            d[i][1] = (f32x4){0.f,0.f,0.f,0.f};
            d[i][0] = __builtin_amdgcn_mfma_f32_16x16x32_bf16(af[0][0], bf[i][0], d[i][0], 0,0,0);
            d[i][0] = __builtin_amdgcn_mfma_f32_16x16x32_bf16(af[0][1], bf[i][1], d[i][0], 0,0,0);
            d[i][1] = __builtin_amdgcn_mfma_f32_16x16x32_bf16(af[1][0], bf[i][0], d[i][1], 0,0,0);
            d[i][1] = __builtin_amdgcn_mfma_f32_16x16x32_bf16(af[1][1], bf[i][1], d[i][1], 0,0,0);
        }
        // C/D: row(edge) = quad*4+reg (+16 for M-tile 1), col = lm
        #pragma unroll
        for (int i = 0; i < 4; ++i) {
            const int coll = (((wv<<2)+i)<<4) + lm;
            #pragma unroll
            for (int r = 0; r < 4; ++r) {
                sh_ew[((quad<<2)+r)*EW_STRIDE + coll]    = d[i][0][r] + b2v[i];
                sh_ew[((quad<<2)+r+16)*EW_STRIDE + coll] = d[i][1][r] + b2v[i];
            }
        }
        __syncthreads();

        // ---- chunk epilogue (region-uniform per chunk) ----
        if (ci < 4) {                       // w_ss: u = ci*8 + j (of 32), w in 0..32
            const int ub = ci << 3;
            #pragma unroll
            for (int k = 0; k < 4; ++k) {
                int p = t + (k<<8); int e = p >> 5; int w = p & 31;
                float s = 0.f;
                #pragma unroll
                for (int j = 0; j < 8; ++j) s += sh_s[e][ub+j] * sh_ew[e*EW_STRIDE + (j<<5)+w];
                outs[k] += 0.125f * s;      // 1/(sqrt(32)*sqrt(2))
            }
        } else if (ci < 6) {                // w_sv: u = (ci-4)*16 + j (of 32), w in 0..16
            const int ub = (ci-4) << 4;
            #pragma unroll
            for (int k = 0; k < 2; ++k) {
                int q = t + (k<<8); int e = q >> 4; int w = q & 15;
                float s = 0.f;
                #pragma unroll
                for (int j = 0; j < 16; ++j) s += sh_s[e][ub+j] * sh_ew[e*EW_STRIDE + (j<<4)+w];
                q2r[k] += s;
            }
            if (ci == 5) {
                #pragma unroll
                for (int k = 0; k < 2; ++k) { int q = t + (k<<8); sh_q2[q>>4][q&15] = q2r[k]; }
            }
        } else if (ci == 6) {               // w_vs: u in 0..16, w in 0..16
            #pragma unroll
            for (int k = 0; k < 6; ++k) {
                int p = t + (k<<8); int e = p/48; int m = p - e*48; int w = m/3; int d2 = m - w*3;
                float s = 0.f;
                #pragma unroll
                for (int u = 0; u < 16; ++u) s += sh_v[e][u*3+d2] * sh_ew[e*EW_STRIDE + (u<<4)+w];
                outv[k] += 0.14433756729740643f * s;   // 1/(sqrt(16)*sqrt(3))
            }
        } else if (ci < 9) {                // w_vv0: u = (ci-7)*8 + j (of 16), w in 0..32
            const int ub = (ci-7) << 3;
            #pragma unroll
            for (int k = 0; k < 4; ++k) {
                int p = t + (k<<8); int e = p >> 5; int w = p & 31;
                float s = 0.f;
                #pragma unroll
                for (int j = 0; j < 8; ++j) s += sh_dot[e][ub+j] * sh_ew[e*EW_STRIDE + (j<<5)+w];
                outs[k] += 0.17677669529663687f * s;   // 1/(sqrt(16)*sqrt(2))
            }
        } else {                            // w_vv1: u in 0..16, w in 0..16 (cross)
            #pragma unroll
            for (int k = 0; k < 6; ++k) {
                int p = t + (k<<8); int e = p/48; int m = p - e*48; int w = m/3; int d2 = m - w*3;
                float s = 0.f;
                #pragma unroll
                for (int u = 0; u < 16; ++u) s += sh_cross[e][u*3+d2] * sh_ew[e*EW_STRIDE + (u<<4)+w];
                outv[k] += 0.14433756729740643f * s;
            }
        }
    }

    // ---- final: scatter messages ----
    #pragma unroll
    for (int k = 0; k < 4; ++k) {
        int p = t + (k<<8); int e = p >> 5; int w = p & 31;
        atomicAdd(&agg[sh_dst[e]*80 + w], outs[k]);
    }
    #pragma unroll
    for (int k = 0; k < 6; ++k) {
        int p = t + (k<<8); int e = p/48; int m = p - e*48; int w = m/3; int d2 = m - w*3;
        float val = outv[k] + sh_q2[e][w]*sh_y1[e][d2]*0.10206207261596574f; // 1/sqrt(96)
        atomicAdd(&agg[sh_dst[e]*80 + 32 + m], val);
    }
    if (t < 32) atomicAdd(&cnt[sh_dst[t]], 1.0f);
}

// ---------------------------------------------------------------------------
// Node kernel: out = agg/max(cnt,1) + self_interaction + h  (fp32 out)
// ---------------------------------------------------------------------------
__global__ __launch_bounds__(256, 4) void node_kernel(
    const float* __restrict__ h, const float* __restrict__ Wss, const float* __restrict__ Wvv,
    const float* __restrict__ agg, const float* __restrict__ cnt,
    float* __restrict__ out)
{
    const int idx = blockIdx.x*256 + threadIdx.x;
    const int n = idx / 80;
    const int j = idx - n*80;
    float a = agg[idx] / fmaxf(cnt[n], 1.0f);
    const float* hrow = h + n*80;
    float si = 0.f;
    if (j < 32) {
        #pragma unroll
        for (int u = 0; u < 32; ++u) si += hrow[u] * Wss[(u<<5)+j];
        si *= 0.17677669529663687f;   // 1/sqrt(32)
    } else {
        int m = j - 32; int w = m/3; int d = m - w*3;
        #pragma unroll
        for (int u = 0; u < 16; ++u) si += hrow[32+u*3+d] * Wvv[(u<<4)+w];
        si *= 0.25f;                  // 1/sqrt(16)
    }
    out[idx] = a + si + hrow[j];
}

extern "C" void kernel_launch(void* const* d_in, const int* in_sizes, int n_in,
                              void* d_out, int out_size, void* d_ws, size_t ws_size,
                              hipStream_t stream) {
    const float* h     = (const float*)d_in[0];
    const float* pos   = (const float*)d_in[1];
    const int*   ei    = (const int*)d_in[2];
    const float* means = (const float*)d_in[3];
    const float* betas = (const float*)d_in[4];
    const float* W1    = (const float*)d_in[5];
    const float* b1    = (const float*)d_in[6];
    const float* W2    = (const float*)d_in[7];
    const float* b2    = (const float*)d_in[8];
    const float* Wss   = (const float*)d_in[9];
    const float* Wvv   = (const float*)d_in[10];

    float* agg = (float*)d_ws;
    float* cnt = agg + (size_t)NN*80;
    u16*   W2T = (u16*)(cnt + NN);          // 2560*64 bf16 = 320 KB

    hipMemsetAsync(d_ws, 0, (size_t)(NN*80 + NN)*sizeof(float), stream);
    hipLaunchKernelGGL(w2_transpose, dim3(WN/64), dim3(256), 0, stream, W2, W2T);
    hipLaunchKernelGGL(edge_kernel, dim3(EE/32), dim3(256), 0, stream,
                       h, pos, ei, means, betas, W1, b1, W2T, b2, agg, cnt);
    hipLaunchKernelGGL(node_kernel, dim3((NN*80)/256), dim3(256), 0, stream,
                       h, Wss, Wvv, agg, cnt, (float*)d_out);
}

// Round 5
// 141.928 us; speedup vs baseline: 2.9403x; 1.0962x over previous
//
#include <hip/hip_runtime.h>
#include <math.h>

#define NN 8192
#define EE 32768
#define WN 2560
#define HID_STRIDE 72            // sh_hidb row stride (bf16)

typedef unsigned short u16;
typedef unsigned int u32;
typedef short short8 __attribute__((ext_vector_type(8)));   // 8 bf16 (MFMA A/B frag)
typedef float f32x4 __attribute__((ext_vector_type(4)));    // MFMA C/D frag

__device__ __forceinline__ u16 f2b(float f) {               // fp32 -> bf16 RNE
    u32 x = __float_as_uint(f);
    return (u16)((x + 0x7fffu + ((x >> 16) & 1u)) >> 16);
}

// ---------------------------------------------------------------------------
// prep: zero agg+cnt (663,552 floats) across 256 blocks; blocks 0..39 also
// transpose W2 [64][2560] fp32 -> W2T [2560][64] bf16 (k contiguous).
// ---------------------------------------------------------------------------
__global__ __launch_bounds__(256) void prep(const float* __restrict__ W2,
                                            u16* __restrict__ W2T,
                                            float* __restrict__ zbase) {
    const int t = threadIdx.x, b = blockIdx.x;
    const float4 z4 = {0.f, 0.f, 0.f, 0.f};
    #pragma unroll
    for (int k = 0; k < 3; ++k) {
        int i = b * 768 + k * 256 + t;          // float4 index
        if (i < 165888) ((float4*)zbase)[i] = z4;   // 165888*4 = 663552 floats
    }
    if (b < 40) {
        __shared__ float tile[64][65];
        const int c0 = b << 6;
        const int tl = t & 63, th = t >> 6;
        #pragma unroll
        for (int r = 0; r < 16; ++r) {
            int kk = (r << 2) + th;
            tile[kk][tl] = W2[kk * WN + c0 + tl];
        }
        __syncthreads();
        #pragma unroll
        for (int r = 0; r < 16; ++r) {
            int c = (r << 2) + th;
            W2T[(size_t)(c0 + c) * 64 + tl] = f2b(tile[tl][c]);
        }
    }
}

// ---------------------------------------------------------------------------
// Edge kernel: 1024 WGs x 256 threads (4 waves), 32 edges per WG.
// Phase A: geometry, rbf, hid->bf16 LDS, pre-scaled coefficient arrays.
// Phase B: 10 chunks x 16 MFMA; contraction stays in registers: each lane
//   holds ew for 8 edges x {w=lm, lm+16} and accumulates region partials
//   with broadcast LDS coefficient reads. NO sh_ew, NO per-chunk barriers.
// Final: one cross-wave reduction through LDS (overlaid on dead phase-A
//   arrays), then atomicAdd scatter into agg/cnt.
// ---------------------------------------------------------------------------
__global__ __launch_bounds__(256, 2) void edge_kernel(
    const float* __restrict__ h, const float* __restrict__ pos, const int* __restrict__ ei,
    const float* __restrict__ means, const float* __restrict__ betas,
    const float* __restrict__ W1, const float* __restrict__ b1,
    const u16* __restrict__ W2T, const float* __restrict__ b2,
    float* __restrict__ agg, float* __restrict__ cnt)
{
    // --- overlaid scratch: phase-A coefficient arrays, then reduction bufs ---
    // phase A layout:  sh_ss[32][33] @0 (4224) | sh_dot[32][17] @4224 (2176) |
    //   sh_v[32][68] @6400 (8704) | sh_cross[32][68] @15104 (8704) |
    //   sh_hidb @23808 (4608)  -> end 28416
    // reduction layout: redS[4][32][33] @0 (16896) | redQ[4][32][17] @16896
    //   (8704) | redV[4][32][49] @25600 (25088) -> end 50688
    __shared__ alignas(16) char sbuf[50688];
    float (*sh_ss)[33]    = (float (*)[33])(sbuf);
    float (*sh_dot)[17]   = (float (*)[17])(sbuf + 4224);
    float (*sh_v)[68]     = (float (*)[68])(sbuf + 6400);
    float (*sh_cross)[68] = (float (*)[68])(sbuf + 15104);
    u16*  sh_hidb         = (u16*)(sbuf + 23808);
    float (*redS)[32][33] = (float (*)[32][33])(sbuf);
    float (*redQ)[32][17] = (float (*)[32][17])(sbuf + 16896);
    float (*redV)[32][49] = (float (*)[32][49])(sbuf + 25600);

    __shared__ float sh_y1[32][3];
    __shared__ float sh_geo[32][2];
    __shared__ int   sh_src[32];
    __shared__ int   sh_dst[32];

    const int t = threadIdx.x;

    // ---- A1: per-edge geometry (threads 0..31) ----
    if (t < 32) {
        const int eg = (blockIdx.x << 5) + t;
        const int si = ei[eg];
        const int di = ei[EE + eg];
        float ax = pos[si*3+0], ay = pos[si*3+1], az = pos[si*3+2];
        float bx = pos[di*3+0], by = pos[di*3+1], bz = pos[di*3+2];
        float vx = bx-ax, vy = by-ay, vz = bz-az;
        float d = sqrtf(vx*vx + vy*vy + vz*vz + 1e-12f);
        float invd = 1.7320508075688772f / d;      // sqrt(3)/d
        sh_y1[t][0] = vx*invd; sh_y1[t][1] = vy*invd; sh_y1[t][2] = vz*invd;
        sh_geo[t][0] = expf(-d);                   // ALPHA = 1
        sh_geo[t][1] = (d < 5.0f) ? 0.5f*(cosf(d*0.6283185307179586f) + 1.0f) : 0.0f;
        sh_src[t] = si; sh_dst[t] = di;
    }
    __syncthreads();

    // ---- A2: rbf + hid(bf16) + pre-scaled coefficients (8 threads/edge) ----
    {
        const int e = t >> 3, r = t & 7;
        const float expd = sh_geo[e][0], cut = sh_geo[e][1];
        float rbf[16];
        #pragma unroll
        for (int k = 0; k < 16; ++k) {
            float td = expd - means[k];
            rbf[k] = expf(-betas[k]*td*td) * cut;
        }
        short8 pk;
        #pragma unroll
        for (int jj = 0; jj < 8; ++jj) {
            int j = (r << 3) + jj;
            float a = b1[j];
            #pragma unroll
            for (int k = 0; k < 16; ++k) a += rbf[k] * W1[(k<<6) + j];
            float s = a / (1.0f + expf(-a));        // silu
            pk[jj] = (short)f2b(s);
        }
        *(short8*)&sh_hidb[e*HID_STRIDE + (r<<3)] = pk;

        const int srcn = sh_src[e];
        const float* hrow = h + srcn*80;
        const float y1x = sh_y1[e][0], y1y = sh_y1[e][1], y1z = sh_y1[e][2];
        #pragma unroll
        for (int i = 0; i < 4; ++i) { int u = (r<<2)+i; sh_ss[e][u] = 0.125f * hrow[u]; }
        #pragma unroll
        for (int i = 0; i < 2; ++i) {
            int u = (r<<1)+i;
            float v0 = hrow[32+u*3+0];
            float v1 = hrow[32+u*3+1];
            float v2 = hrow[32+u*3+2];
            sh_v[e][(u<<2)+0] = v0 * 0.14433756729740643f;   // p3 scale folded
            sh_v[e][(u<<2)+1] = v1 * 0.14433756729740643f;
            sh_v[e][(u<<2)+2] = v2 * 0.14433756729740643f;
            sh_dot[e][u] = (v0*y1x + v1*y1y + v2*y1z) * 0.10206207261596574f; // /sqrt3 * p4 scale
            sh_cross[e][(u<<2)+0] = (v1*y1z - v2*y1y) * 0.10206207261596574f; // /sqrt2 * p5 scale
            sh_cross[e][(u<<2)+1] = (v2*y1x - v0*y1z) * 0.10206207261596574f;
            sh_cross[e][(u<<2)+2] = (v0*y1y - v1*y1x) * 0.10206207261596574f;
        }
    }
    __syncthreads();   // publish phase A

    // ---- A-fragments: hid rows (regs for all 160 col tiles) ----
    const int ln = t & 63, wv = t >> 6;
    const int quad = ln >> 4, lm = ln & 15;
    short8 af[2][2];   // [M-tile][K-step]; A[m=lm][k=ks*32+quad*8+j]
    #pragma unroll
    for (int mt = 0; mt < 2; ++mt)
        #pragma unroll
        for (int ks = 0; ks < 2; ++ks)
            af[mt][ks] = *(const short8*)&sh_hidb[(mt*16+lm)*HID_STRIDE + (ks<<5) + (quad<<3)];

    // ---- Phase B: chunks, register-resident contraction ----
    float accS[2][4][2];   // [mt][r][half]: out_s partial at (e, w=lm / lm+16)
    float accQ[2][4];      // q2 partial at (e, w=lm), scaled by 0.125
    float accV[2][4][3];   // (p3+p5) partial at (e, w=lm, d)
    #pragma unroll
    for (int mt = 0; mt < 2; ++mt)
        #pragma unroll
        for (int r = 0; r < 4; ++r) {
            accS[mt][r][0] = accS[mt][r][1] = 0.f;
            accQ[mt][r] = 0.f;
            accV[mt][r][0] = accV[mt][r][1] = accV[mt][r][2] = 0.f;
        }

    #pragma unroll
    for (int ci = 0; ci < 10; ++ci) {
        short8 bfr[4][2];
        float b2v[4];
        #pragma unroll
        for (int i = 0; i < 4; ++i) {
            const int coll = (((wv<<2)+i)<<4) + lm;
            const int col  = (ci<<8) + coll;
            bfr[i][0] = *(const short8*)(W2T + (size_t)col*64 + (quad<<3));
            bfr[i][1] = *(const short8*)(W2T + (size_t)col*64 + 32 + (quad<<3));
            b2v[i] = b2[col];
        }
        f32x4 d[4][2];
        #pragma unroll
        for (int i = 0; i < 4; ++i) {
            d[i][0] = (f32x4){0.f,0.f,0.f,0.f};
            d[i][1] = (f32x4){0.f,0.f,0.f,0.f};
            d[i][0] = __builtin_amdgcn_mfma_f32_16x16x32_bf16(af[0][0], bfr[i][0], d[i][0], 0,0,0);
            d[i][0] = __builtin_amdgcn_mfma_f32_16x16x32_bf16(af[0][1], bfr[i][1], d[i][0], 0,0,0);
            d[i][1] = __builtin_amdgcn_mfma_f32_16x16x32_bf16(af[1][0], bfr[i][0], d[i][1], 0,0,0);
            d[i][1] = __builtin_amdgcn_mfma_f32_16x16x32_bf16(af[1][1], bfr[i][1], d[i][1], 0,0,0);
            d[i][0] += b2v[i];     // ew = matmul + b2 (all 4 rows, same col)
            d[i][1] += b2v[i];
        }

        if (ci < 4) {                       // w_ss: w=coll&31, j=coll>>5=2wv+(i>=2)
            const int ub = (ci<<3) + (wv<<1);
            #pragma unroll
            for (int mt = 0; mt < 2; ++mt)
                #pragma unroll
                for (int r = 0; r < 4; ++r) {
                    const int e = (mt<<4) + (quad<<2) + r;
                    float s0 = sh_ss[e][ub], s1 = sh_ss[e][ub+1];
                    accS[mt][r][0] += s0*d[0][mt][r] + s1*d[2][mt][r];
                    accS[mt][r][1] += s0*d[1][mt][r] + s1*d[3][mt][r];
                }
        } else if (ci < 6) {                // w_sv: w=lm, u=(ci-4)*16+wv*4+i
            const int ub = ((ci-4)<<4) + (wv<<2);
            #pragma unroll
            for (int mt = 0; mt < 2; ++mt)
                #pragma unroll
                for (int r = 0; r < 4; ++r) {
                    const int e = (mt<<4) + (quad<<2) + r;
                    float a = 0.f;
                    #pragma unroll
                    for (int i = 0; i < 4; ++i) a += sh_ss[e][ub+i] * d[i][mt][r];
                    accQ[mt][r] += a;
                }
        } else if (ci == 6) {               // w_vs: w=lm, u=wv*4+i
            const int ub = wv << 2;
            #pragma unroll
            for (int mt = 0; mt < 2; ++mt)
                #pragma unroll
                for (int r = 0; r < 4; ++r) {
                    const int e = (mt<<4) + (quad<<2) + r;
                    #pragma unroll
                    for (int i = 0; i < 4; ++i) {
                        const float4 vv = *(const float4*)&sh_v[e][(ub+i)<<2];
                        float ew = d[i][mt][r];
                        accV[mt][r][0] += vv.x * ew;
                        accV[mt][r][1] += vv.y * ew;
                        accV[mt][r][2] += vv.z * ew;
                    }
                }
        } else if (ci < 9) {                // w_vv0: like ss with dot (pre-scaled)
            const int ub = ((ci-7)<<3) + (wv<<1);
            #pragma unroll
            for (int mt = 0; mt < 2; ++mt)
                #pragma unroll
                for (int r = 0; r < 4; ++r) {
                    const int e = (mt<<4) + (quad<<2) + r;
                    float s0 = sh_dot[e][ub], s1 = sh_dot[e][ub+1];
                    accS[mt][r][0] += s0*d[0][mt][r] + s1*d[2][mt][r];
                    accS[mt][r][1] += s0*d[1][mt][r] + s1*d[3][mt][r];
                }
        } else {                            // w_vv1: like vs with cross (pre-scaled)
            const int ub = wv << 2;
            #pragma unroll
            for (int mt = 0; mt < 2; ++mt)
                #pragma unroll
                for (int r = 0; r < 4; ++r) {
                    const int e = (mt<<4) + (quad<<2) + r;
                    #pragma unroll
                    for (int i = 0; i < 4; ++i) {
                        const float4 cc = *(const float4*)&sh_cross[e][(ub+i)<<2];
                        float ew = d[i][mt][r];
                        accV[mt][r][0] += cc.x * ew;
                        accV[mt][r][1] += cc.y * ew;
                        accV[mt][r][2] += cc.z * ew;
                    }
                }
        }
    }

    __syncthreads();   // phase-A coefficient reads done; safe to overlay red*

    #pragma unroll
    for (int mt = 0; mt < 2; ++mt)
        #pragma unroll
        for (int r = 0; r < 4; ++r) {
            const int e = (mt<<4) + (quad<<2) + r;
            redS[wv][e][lm]      = accS[mt][r][0];
            redS[wv][e][lm+16]   = accS[mt][r][1];
            redQ[wv][e][lm]      = accQ[mt][r];
            redV[wv][e][lm*3+0]  = accV[mt][r][0];
            redV[wv][e][lm*3+1]  = accV[mt][r][1];
            redV[wv][e][lm*3+2]  = accV[mt][r][2];
        }
    __syncthreads();

    // ---- final: cross-wave sum + scatter ----
    #pragma unroll
    for (int k = 0; k < 4; ++k) {
        int p = t + (k<<8); int e = p >> 5; int w = p & 31;
        float v = redS[0][e][w] + redS[1][e][w] + redS[2][e][w] + redS[3][e][w];
        atomicAdd(&agg[sh_dst[e]*80 + w], v);
    }
    #pragma unroll
    for (int k = 0; k < 6; ++k) {
        int p = t + (k<<8); int e = p/48; int m = p - e*48; int w = m/3; int dd = m - w*3;
        float pv = redV[0][e][m] + redV[1][e][m] + redV[2][e][m] + redV[3][e][m];
        float q2 = redQ[0][e][w] + redQ[1][e][w] + redQ[2][e][w] + redQ[3][e][w];
        // q2 was accumulated with 0.125-scaled s; true p2 term = q2/0.125*y1/sqrt(96)
        float val = pv + q2 * sh_y1[e][dd] * 0.8164965809277261f;
        atomicAdd(&agg[sh_dst[e]*80 + 32 + m], val);
    }
    if (t < 32) atomicAdd(&cnt[sh_dst[t]], 1.0f);
}

// ---------------------------------------------------------------------------
// Node kernel: out = agg/max(cnt,1) + self_interaction + h  (fp32 out)
// ---------------------------------------------------------------------------
__global__ __launch_bounds__(256, 4) void node_kernel(
    const float* __restrict__ h, const float* __restrict__ Wss, const float* __restrict__ Wvv,
    const float* __restrict__ agg, const float* __restrict__ cnt,
    float* __restrict__ out)
{
    const int idx = blockIdx.x*256 + threadIdx.x;
    const int n = idx / 80;
    const int j = idx - n*80;
    float a = agg[idx] / fmaxf(cnt[n], 1.0f);
    const float* hrow = h + n*80;
    float si = 0.f;
    if (j < 32) {
        #pragma unroll
        for (int u = 0; u < 32; ++u) si += hrow[u] * Wss[(u<<5)+j];
        si *= 0.17677669529663687f;   // 1/sqrt(32)
    } else {
        int m = j - 32; int w = m/3; int d = m - w*3;
        #pragma unroll
        for (int u = 0; u < 16; ++u) si += hrow[32+u*3+d] * Wvv[(u<<4)+w];
        si *= 0.25f;                  // 1/sqrt(16)
    }
    out[idx] = a + si + hrow[j];
}

extern "C" void kernel_launch(void* const* d_in, const int* in_sizes, int n_in,
                              void* d_out, int out_size, void* d_ws, size_t ws_size,
                              hipStream_t stream) {
    const float* h     = (const float*)d_in[0];
    const float* pos   = (const float*)d_in[1];
    const int*   ei    = (const int*)d_in[2];
    const float* means = (const float*)d_in[3];
    const float* betas = (const float*)d_in[4];
    const float* W1    = (const float*)d_in[5];
    const float* b1    = (const float*)d_in[6];
    const float* W2    = (const float*)d_in[7];
    const float* b2    = (const float*)d_in[8];
    const float* Wss   = (const float*)d_in[9];
    const float* Wvv   = (const float*)d_in[10];

    float* agg = (float*)d_ws;
    float* cnt = agg + (size_t)NN*80;
    u16*   W2T = (u16*)(cnt + NN);          // 2560*64 bf16 = 320 KB

    hipLaunchKernelGGL(prep, dim3(256), dim3(256), 0, stream, W2, W2T, agg);
    hipLaunchKernelGGL(edge_kernel, dim3(EE/32), dim3(256), 0, stream,
                       h, pos, ei, means, betas, W1, b1, W2T, b2, agg, cnt);
    hipLaunchKernelGGL(node_kernel, dim3((NN*80)/256), dim3(256), 0, stream,
                       h, Wss, Wvv, agg, cnt, (float*)d_out);
}